// Round 10
// baseline (289.730 us; speedup 1.0000x reference)
//
#include <hip/hip_runtime.h>
#include <hip/hip_bf16.h>
#include <math.h>

#define IN_DIM 128
#define HID 64
#define NREL 2

using f32x4 = __attribute__((ext_vector_type(4))) float;
using s16x8 = __attribute__((ext_vector_type(8))) short;

// fp32 -> bf16 (RNE) and back, via bit ops
__device__ __forceinline__ short f2bf(float f) {
    unsigned u = __float_as_uint(f);
    unsigned r = (u + 0x7fffu + ((u >> 16) & 1u)) >> 16;
    return (short)r;
}
__device__ __forceinline__ float bf2f(short b) {
    return __uint_as_float(((unsigned)(unsigned short)b) << 16);
}

// ---------------------------------------------------------------------------
// W repack into MFMA B-fragment order, split hi/lo bf16.
// ---------------------------------------------------------------------------
__device__ __forceinline__ void repack_one(const float* Wa, const float* Wb,
                                           const float* Wr, short* Wf, int T,
                                           int idx) {
    int g = idx >> 9;
    int r = idx & 511;
    int lane = r >> 3;
    int j = r & 7;
    int part = g & 1;
    int ct = g >> 1;
    int t = ct % T;
    int c = ct / T;
    int col = c * 16 + (lane & 15);
    int k = t * 32 + ((lane >> 4) << 3) + j;
    const float* Wg = (col < 64) ? Wa : (col < 128) ? Wb : Wr;
    float v = Wg[(size_t)k * 64 + (col & 63)];
    short hi = f2bf(v);
    Wf[idx] = part ? f2bf(v - bf2f(hi)) : hi;
}

// ---------------------------------------------------------------------------
// Prep kernel: zero cnt2 (role A) + repack W fragments (role B), fused.
// ---------------------------------------------------------------------------
__global__ void prep_kernel(int* __restrict__ cnt, int n2,
                            const float* __restrict__ W1,
                            const float* __restrict__ root1,
                            const float* __restrict__ W2,
                            const float* __restrict__ root2,
                            short* __restrict__ Wf1, short* __restrict__ Wf2,
                            int zero_blocks) {
    const int b = blockIdx.x;
    if (b < zero_blocks) {
        int i = b * 256 + threadIdx.x;
        if (i < n2) cnt[i] = 0;
    } else {
        const int L1 = 12 * 4 * 2 * 512;  // 49152
        const int L2c = 12 * 2 * 2 * 512; // 24576
        int tid = (b - zero_blocks) * 256 + threadIdx.x;
        if (tid < L1) {
            repack_one(W1, W1 + (size_t)IN_DIM * 64, root1, Wf1, 4, tid);
        } else if (tid < L1 + L2c) {
            repack_one(W2, W2 + (size_t)HID * 64, root2, Wf2, 2, tid - L1);
        }
    }
}

// ---------------------------------------------------------------------------
// CSR build: count edges per (rel, dst)  [2N buckets, for per-rel inv-deg]
// ---------------------------------------------------------------------------
__global__ void count_edges(const int* __restrict__ et, const int* __restrict__ dst,
                            int* __restrict__ cnt, int E, int N) {
    int e = blockIdx.x * blockDim.x + threadIdx.x;
    if (e < E) {
        atomicAdd(&cnt[et[e] * N + dst[e]], 1);
    }
}

// ---------------------------------------------------------------------------
// Scan phase 1 (paired-sum option) / phase 3
// ---------------------------------------------------------------------------
#define SCAN_T 256
#define SCAN_I 4
__global__ void scan_phase1(const int* __restrict__ in, const int* __restrict__ in2,
                            int* __restrict__ excl, int* __restrict__ bsum, int n) {
    __shared__ int sdata[SCAN_T];
    int b = blockIdx.x;
    int t = threadIdx.x;
    int base = b * SCAN_T * SCAN_I;
    int v[SCAN_I];
    int s = 0;
#pragma unroll
    for (int i = 0; i < SCAN_I; ++i) {
        int idx = base + t * SCAN_I + i;
        v[i] = (idx < n) ? (in2 ? in[idx] + in2[idx] : in[idx]) : 0;
        s += v[i];
    }
    sdata[t] = s;
    __syncthreads();
    for (int off = 1; off < SCAN_T; off <<= 1) {
        int x = (t >= off) ? sdata[t - off] : 0;
        __syncthreads();
        sdata[t] += x;
        __syncthreads();
    }
    int run = sdata[t] - s;
    if (bsum && t == SCAN_T - 1) bsum[b] = sdata[SCAN_T - 1];
#pragma unroll
    for (int i = 0; i < SCAN_I; ++i) {
        int idx = base + t * SCAN_I + i;
        if (idx < n) excl[idx] = run;
        run += v[i];
    }
}

__global__ void scan_phase3(const int* __restrict__ excl, const int* __restrict__ boff,
                            int* __restrict__ rowptr, int* __restrict__ cursor,
                            int n, int total) {
    int i = blockIdx.x * blockDim.x + threadIdx.x;
    if (i < n) {
        int v = excl[i] + boff[i / (SCAN_T * SCAN_I)];
        rowptr[i] = v;
        cursor[i] = v;
    }
    if (i == 0) rowptr[n] = total;
}

// ---------------------------------------------------------------------------
// Split-bf16 MFMA GEMM body (R6 variant: no LDS, no barriers).
// Block = 4 waves = 2 row-tiles x 2 col-halves = 32 rows. All X loads issued
// up-front; 6 col-tiles per wave, Wf fragments double-buffered.
// ---------------------------------------------------------------------------
template <int K>
__device__ __forceinline__ void gemm_body(
    int bid, const float* __restrict__ X, const short* __restrict__ Wf,
    float* __restrict__ PA, float* __restrict__ PB, float* __restrict__ PR,
    int M) {
    constexpr int T = K / 32;
    const int lane = threadIdx.x & 63;
    const int wid = threadIdx.x >> 6;
    const int row0 = bid * 32 + (wid >> 1) * 16;
    const int cbase = (wid & 1) * 6;

    int arow = row0 + (lane & 15);
    if (arow > M - 1) arow = M - 1;
    const float* xr = X + (size_t)arow * K + ((lane >> 4) << 3);
    const s16x8* WfV = (const s16x8*)Wf;

    float4 xa[T][2];
#pragma unroll
    for (int t = 0; t < T; ++t) {
        xa[t][0] = *reinterpret_cast<const float4*>(xr + t * 32);
        xa[t][1] = *reinterpret_cast<const float4*>(xr + t * 32 + 4);
    }
    s16x8 ah[T], al[T];
#pragma unroll
    for (int t = 0; t < T; ++t) {
        const float av[8] = {xa[t][0].x, xa[t][0].y, xa[t][0].z, xa[t][0].w,
                             xa[t][1].x, xa[t][1].y, xa[t][1].z, xa[t][1].w};
#pragma unroll
        for (int j = 0; j < 8; ++j) {
            short h = f2bf(av[j]);
            ah[t][j] = h;
            al[t][j] = f2bf(av[j] - bf2f(h));
        }
    }

    f32x4 acc[6];
#pragma unroll
    for (int c = 0; c < 6; ++c) acc[c] = (f32x4){0.f, 0.f, 0.f, 0.f};

    s16x8 bhA[T], blA[T], bhB[T], blB[T];

#define LOADB(H, L, CG)                                                       \
    {                                                                         \
        _Pragma("unroll") for (int t = 0; t < T; ++t) {                       \
            H[t] = WfV[(size_t)(((CG) * T + t) * 2 + 0) * 64 + lane];         \
            L[t] = WfV[(size_t)(((CG) * T + t) * 2 + 1) * 64 + lane];         \
        }                                                                     \
    }
#define DOMFMA(H, L, CI)                                                      \
    {                                                                         \
        _Pragma("unroll") for (int t = 0; t < T; ++t) {                       \
            acc[CI] = __builtin_amdgcn_mfma_f32_16x16x32_bf16(ah[t], H[t],    \
                                                              acc[CI], 0, 0, 0); \
            acc[CI] = __builtin_amdgcn_mfma_f32_16x16x32_bf16(al[t], H[t],    \
                                                              acc[CI], 0, 0, 0); \
            acc[CI] = __builtin_amdgcn_mfma_f32_16x16x32_bf16(ah[t], L[t],    \
                                                              acc[CI], 0, 0, 0); \
        }                                                                     \
    }

    LOADB(bhA, blA, cbase + 0);
    LOADB(bhB, blB, cbase + 1);
    DOMFMA(bhA, blA, 0);
    LOADB(bhA, blA, cbase + 2);
    DOMFMA(bhB, blB, 1);
    LOADB(bhB, blB, cbase + 3);
    DOMFMA(bhA, blA, 2);
    LOADB(bhA, blA, cbase + 4);
    DOMFMA(bhB, blB, 3);
    LOADB(bhB, blB, cbase + 5);
    DOMFMA(bhA, blA, 4);
    DOMFMA(bhB, blB, 5);

#undef LOADB
#undef DOMFMA

    const int drow = row0 + ((lane >> 4) << 2);
    const int dcol = lane & 15;
#pragma unroll
    for (int ci = 0; ci < 6; ++ci) {
        const int cg = cbase + ci;
        float* base = (cg < 4) ? PA : (cg < 8) ? PB : PR;
        const int cc = (cg & 3) * 16 + dcol;
#pragma unroll
        for (int q = 0; q < 4; ++q) {
            const int row = drow + q;
            if (row < M) base[(size_t)row * 64 + cc] = acc[ci][q];
        }
    }
}

// ---------------------------------------------------------------------------
// Fused layer-1 GEMM + CSR fill: each block computes its gemm tile, then
// processes a grid-strided chunk of edges (independent work; fill's atomic/
// store latency hides under the gemm's latency-bound execution).
// ---------------------------------------------------------------------------
template <int K>
__global__ __launch_bounds__(256) void gemm_fill_kernel(
    const float* __restrict__ X, const short* __restrict__ Wf,
    float* __restrict__ PA, float* __restrict__ PB, float* __restrict__ PR,
    int M,
    const int* __restrict__ et, const int* __restrict__ esrc,
    const int* __restrict__ edst, const int* __restrict__ cnt2,
    int* __restrict__ cursor, int2* __restrict__ colw, int E, int N) {
    gemm_body<K>(blockIdx.x, X, Wf, PA, PB, PR, M);

    // ---- fill tail (grid-strided) ----
    const int stride = gridDim.x * 256;
    for (int e = blockIdx.x * 256 + threadIdx.x; e < E; e += stride) {
        int d = edst[e];
        int r = et[e];
        int s = esrc[e];
        int slot = atomicAdd(&cursor[d], 1);
        int deg = cnt2[r * N + d];
        float iw = 1.f / (float)deg;
        unsigned long long v = (unsigned long long)(unsigned)(r * N + s) |
                               ((unsigned long long)__float_as_uint(iw) << 32);
        __builtin_nontemporal_store(v, (unsigned long long*)(colw + slot));
    }
}

// ---------------------------------------------------------------------------
// Standalone GEMM (layer 2)
// ---------------------------------------------------------------------------
template <int K>
__global__ __launch_bounds__(256) void gemm_kernel(
    const float* __restrict__ X, const short* __restrict__ Wf,
    float* __restrict__ PA, float* __restrict__ PB, float* __restrict__ PR,
    int M) {
    gemm_body<K>(blockIdx.x, X, Wf, PA, PB, PR, M);
}

// ---------------------------------------------------------------------------
// Aggregate + LayerNorm (+ optional exact GELU), fused single edge loop.
// ---------------------------------------------------------------------------
__device__ __forceinline__ float4 shfl_xor_f4(float4 v, int m) {
    return make_float4(__shfl_xor(v.x, m), __shfl_xor(v.y, m),
                       __shfl_xor(v.z, m), __shfl_xor(v.w, m));
}

__global__ __launch_bounds__(256) void agg_ln_kernel(
    const float* __restrict__ Pcat,   // [2N,64] = PA|PB
    const float* __restrict__ PR,
    const int* __restrict__ rowptr,   // [N+1], dst-grouped
    const int2* __restrict__ colw,    // [E] {row, invdeg bits}
    const float* __restrict__ bias, const float* __restrict__ g,
    const float* __restrict__ beta,
    float* __restrict__ out, int N, int gelu) {
    const int t = threadIdx.x;
    const int lane = t & 63;
    const int sub = lane >> 4;
    const int c = lane & 15;
    const int node = blockIdx.x * 4 + (t >> 6);
    if (node >= N) return;

    const int c4 = c * 4;
    float4 acc = *reinterpret_cast<const float4*>(PR + (size_t)node * 64 + c4);
    {
        float4 b4 = *reinterpret_cast<const float4*>(bias + c4);
        acc.x += b4.x; acc.y += b4.y; acc.z += b4.z; acc.w += b4.w;
    }

    const int beg = rowptr[node];
    const int end = rowptr[node + 1];
    float4 s0 = make_float4(0.f, 0.f, 0.f, 0.f);
    float4 s1 = s0, s2 = s0, s3 = s0;
    for (int i = beg + sub; i < end; i += 16) {
        {
            const int2 w = colw[i];
            const float4 v = *reinterpret_cast<const float4*>(Pcat + w.x * 64 + c4);
            const float f = __int_as_float(w.y);
            s0.x = fmaf(v.x, f, s0.x); s0.y = fmaf(v.y, f, s0.y);
            s0.z = fmaf(v.z, f, s0.z); s0.w = fmaf(v.w, f, s0.w);
        }
        int j = i + 4;
        if (j < end) {
            const int2 w = colw[j];
            const float4 v = *reinterpret_cast<const float4*>(Pcat + w.x * 64 + c4);
            const float f = __int_as_float(w.y);
            s1.x = fmaf(v.x, f, s1.x); s1.y = fmaf(v.y, f, s1.y);
            s1.z = fmaf(v.z, f, s1.z); s1.w = fmaf(v.w, f, s1.w);
        }
        j = i + 8;
        if (j < end) {
            const int2 w = colw[j];
            const float4 v = *reinterpret_cast<const float4*>(Pcat + w.x * 64 + c4);
            const float f = __int_as_float(w.y);
            s2.x = fmaf(v.x, f, s2.x); s2.y = fmaf(v.y, f, s2.y);
            s2.z = fmaf(v.z, f, s2.z); s2.w = fmaf(v.w, f, s2.w);
        }
        j = i + 12;
        if (j < end) {
            const int2 w = colw[j];
            const float4 v = *reinterpret_cast<const float4*>(Pcat + w.x * 64 + c4);
            const float f = __int_as_float(w.y);
            s3.x = fmaf(v.x, f, s3.x); s3.y = fmaf(v.y, f, s3.y);
            s3.z = fmaf(v.z, f, s3.z); s3.w = fmaf(v.w, f, s3.w);
        }
    }
    s0.x += s1.x + s2.x + s3.x;
    s0.y += s1.y + s2.y + s3.y;
    s0.z += s1.z + s2.z + s3.z;
    s0.w += s1.w + s2.w + s3.w;
    float4 o = shfl_xor_f4(s0, 16);
    s0.x += o.x; s0.y += o.y; s0.z += o.z; s0.w += o.w;
    o = shfl_xor_f4(s0, 32);
    s0.x += o.x; s0.y += o.y; s0.z += o.z; s0.w += o.w;
    acc.x += s0.x; acc.y += s0.y; acc.z += s0.z; acc.w += s0.w;

    // LayerNorm over 64 features (16 lanes x float4; replicated x4 subs)
    float ps = acc.x + acc.y + acc.z + acc.w;
#pragma unroll
    for (int off = 1; off <= 8; off <<= 1) ps += __shfl_xor(ps, off);
    const float mu = ps * (1.f / 64.f);
    const float4 d = make_float4(acc.x - mu, acc.y - mu, acc.z - mu, acc.w - mu);
    float vs = d.x * d.x + d.y * d.y + d.z * d.z + d.w * d.w;
#pragma unroll
    for (int off = 1; off <= 8; off <<= 1) vs += __shfl_xor(vs, off);
    const float rstd = 1.f / sqrtf(vs * (1.f / 64.f) + 1e-5f);

    const float4 g4 = *reinterpret_cast<const float4*>(g + c4);
    const float4 be4 = *reinterpret_cast<const float4*>(beta + c4);
    float4 y;
    y.x = d.x * rstd * g4.x + be4.x;
    y.y = d.y * rstd * g4.y + be4.y;
    y.z = d.z * rstd * g4.z + be4.z;
    y.w = d.w * rstd * g4.w + be4.w;

    if (gelu) {
        y.x = 0.5f * y.x * (1.f + erff(y.x * 0.70710678118654752440f));
        y.y = 0.5f * y.y * (1.f + erff(y.y * 0.70710678118654752440f));
        y.z = 0.5f * y.z * (1.f + erff(y.z * 0.70710678118654752440f));
        y.w = 0.5f * y.w * (1.f + erff(y.w * 0.70710678118654752440f));
    }

    if (sub == 0)
        *reinterpret_cast<float4*>(out + (size_t)node * 64 + c4) = y;
}

// ---------------------------------------------------------------------------
// Launch
// ---------------------------------------------------------------------------
extern "C" void kernel_launch(void* const* d_in, const int* in_sizes, int n_in,
                              void* d_out, int out_size, void* d_ws, size_t ws_size,
                              hipStream_t stream) {
    const float* x = (const float*)d_in[0];
    const int* ei = (const int*)d_in[1];   // [2][E]: src row then dst row
    const int* et = (const int*)d_in[2];   // [E]
    const float* W1 = (const float*)d_in[3];    // [2][128][64]
    const float* root1 = (const float*)d_in[4]; // [128][64]
    const float* b1 = (const float*)d_in[5];
    const float* g1 = (const float*)d_in[6];
    const float* beta1 = (const float*)d_in[7];
    const float* W2 = (const float*)d_in[8];    // [2][64][64]
    const float* root2 = (const float*)d_in[9]; // [64][64]
    const float* b2 = (const float*)d_in[10];
    const float* g2 = (const float*)d_in[11];
    const float* beta2 = (const float*)d_in[12];

    const int E = in_sizes[2];
    const int N = in_sizes[0] / IN_DIM;

    const int WF1 = 12 * 4 * 2 * 512;  // 49152 shorts
    const int WF2 = 12 * 2 * 2 * 512;  // 24576 shorts

    // workspace layout: Wf packs, float bufs, colw (8B-aligned), int bufs
    short* Wf1 = (short*)d_ws;
    short* Wf2 = Wf1 + WF1;
    float* Pcat = (float*)(Wf2 + WF2);           // [2N,64] = PA|PB
    float* PR   = Pcat + (size_t)2 * N * 64;
    float* H    = PR + (size_t)N * 64;
    int2* colw  = (int2*)(H + (size_t)N * 64);   // E entries, 8B aligned
    int* cnt2   = (int*)(colw + E);              // 2N
    int* excl   = cnt2 + 2 * N;                  // N
    int* rowptr = excl + N;                      // N+1
    int* cursor = rowptr + N + 1;                // N
    int* bsum   = cursor + N;                    // 256
    int* boff   = bsum + 256;                    // 256

    const int* esrc = ei;
    const int* edst = ei + E;

    // ---- prep: zero cnt2 + repack W fragments (fused) ----
    int zero_blocks = (2 * N + 255) / 256;
    int rep_blocks = (WF1 + WF2 + 255) / 256;
    prep_kernel<<<zero_blocks + rep_blocks, 256, 0, stream>>>(
        cnt2, 2 * N, W1, root1, W2, root2, Wf1, Wf2, zero_blocks);

    // ---- CSR count + scan ----
    count_edges<<<(E + 255) / 256, 256, 0, stream>>>(et, edst, cnt2, E, N);
    int nb = (N + SCAN_T * SCAN_I - 1) / (SCAN_T * SCAN_I);
    scan_phase1<<<nb, SCAN_T, 0, stream>>>(cnt2, cnt2 + N, excl, bsum, N);
    scan_phase1<<<1, SCAN_T, 0, stream>>>(bsum, nullptr, boff, nullptr, nb);
    scan_phase3<<<(N + 255) / 256, 256, 0, stream>>>(excl, boff, rowptr, cursor, N, E);

    // ---- Layer 1 GEMM + CSR fill (fused) ----
    int gblocks = (N + 31) / 32;
    gemm_fill_kernel<IN_DIM><<<gblocks, 256, 0, stream>>>(
        x, Wf1, Pcat, Pcat + (size_t)N * 64, PR, N,
        et, esrc, edst, cnt2, cursor, colw, E, N);
    agg_ln_kernel<<<(N + 3) / 4, 256, 0, stream>>>(Pcat, PR, rowptr, colw, b1, g1,
                                                   beta1, H, N, 1);

    // ---- Layer 2 ----
    gemm_kernel<HID><<<gblocks, 256, 0, stream>>>(
        H, Wf2, Pcat, Pcat + (size_t)N * 64, PR, N);
    agg_ln_kernel<<<(N + 3) / 4, 256, 0, stream>>>(Pcat, PR, rowptr, colw, b2, g2,
                                                   beta2, (float*)d_out, N, 0);
}